// Round 9
// baseline (156.861 us; speedup 1.0000x reference)
//
#include <hip/hip_runtime.h>
#include <hip/hip_bf16.h>

// LSTM cell fused kernels for MI355X (gfx950).
// B=65536, H=256. R9: two-kernel split with pre-swizzled combine.
//  Prep: comb = bf16(input+hidden) stored in the exact (XOR-swizzled) LDS tile
//        image + weight pack. Pure streaming (~5.4 TB/s measured in R7).
//  Main: 8192 blocks x 256 thr, tile 32r x 64j, acc=32 regs -> 6 blocks/CU.
//        Staging = 4 global_load_lds per wave (zero VALU, zero staging regs).

typedef __attribute__((ext_vector_type(8))) short short8;   // 8 bf16
typedef __attribute__((ext_vector_type(4))) float f32x4;

static constexpr int Bsz  = 65536;
static constexpr int Hdim = 256;
static constexpr size_t COMB_SHORTS = (size_t)Bsz * Hdim;        // 33.5 MB
static constexpr size_t WS_NEED = COMB_SHORTS * 2 + 512 * 1024;

// float -> bf16 bits, round-to-nearest-even
__device__ __forceinline__ short f2bf(float f) {
    unsigned u = __float_as_uint(f);
    return (short)((u + 0x7FFFu + ((u >> 16) & 1u)) >> 16);
}
__device__ __forceinline__ float sigm(float x) { return 1.0f / (1.0f + __expf(-x)); }
__device__ __forceinline__ float tanh_fast(float x) {
    return 2.0f / (1.0f + __expf(-2.0f * x)) - 1.0f;
}

// ---------------------------------------------------------------------------
// Prep. Blocks [0,1024): pack weights (verified layout):
//   flat o = (((g*8 + ks)*16 + jf)*64 + lane)*8 + e
//   k = ks*32 + (lane>>4)*8 + e ; j = jf*16 + (lane&15) ; B[k][j] = W_g[j][k]
// Blocks [1024,9216): comb tile image. 32-row tiles of 16 KB; within tile,
// the 16B chunk for (row rl, k-chunk ci) lands at byte
//   (rl*512 + ci*16) ^ ((rl&7)<<4)
// i.e. exactly the swizzled LDS layout the main kernel's ds_reads expect.
// Consecutive threads write consecutive-XORed 16B chunks -> coalesced.
// ---------------------------------------------------------------------------
__global__ void __launch_bounds__(256)
prep_kernel(const float* __restrict__ inp, const float* __restrict__ hid,
            const float* __restrict__ Wf, const float* __restrict__ Wc,
            const float* __restrict__ Wi, const float* __restrict__ Wo,
            short* __restrict__ comb, short* __restrict__ Bp)
{
    int bid = blockIdx.x;
    if (bid < 1024) {
        int o    = bid * 256 + threadIdx.x;   // 0 .. 262143
        int e    = o & 7;
        int lane = (o >> 3) & 63;
        int jf   = (o >> 9) & 15;
        int ks   = (o >> 13) & 7;
        int g    = (o >> 16) & 3;
        int k = ks * 32 + (lane >> 4) * 8 + e;
        int j = jf * 16 + (lane & 15);
        const float* W = (g == 0) ? Wf : (g == 1) ? Wc : (g == 2) ? Wi : Wo;
        Bp[o] = f2bf(W[j * 256 + k]);
    } else {
        int c   = (bid - 1024) * 256 + threadIdx.x;   // 16B-chunk id 0..2097151
        int row = c >> 5;                             // batch row
        int ci  = c & 31;                             // k-chunk within row
        const float4* ip = reinterpret_cast<const float4*>(inp + (size_t)row * Hdim + ci * 8);
        const float4* hp = reinterpret_cast<const float4*>(hid + (size_t)row * Hdim + ci * 8);
        float4 a0 = ip[0], a1 = ip[1];
        float4 h0 = hp[0], h1 = hp[1];
        short8 v;
        v[0] = f2bf(a0.x + h0.x);
        v[1] = f2bf(a0.y + h0.y);
        v[2] = f2bf(a0.z + h0.z);
        v[3] = f2bf(a0.w + h0.w);
        v[4] = f2bf(a1.x + h1.x);
        v[5] = f2bf(a1.y + h1.y);
        v[6] = f2bf(a1.z + h1.z);
        v[7] = f2bf(a1.w + h1.w);
        int rl   = row & 31;
        int byte = (rl * 512 + ci * 16) ^ ((rl & 7) << 4);
        *reinterpret_cast<short8*>(
            reinterpret_cast<char*>(comb) + (size_t)(row >> 5) * 16384 + byte) = v;
    }
}

// ---------------------------------------------------------------------------
// Main. 8192 blocks x 256 threads (4 waves). Block = 32 rows x 64 gate-cols
// (j-quarter) x 4 gates; wave owns 16 j. acc[4][2] = 32 VGPRs -> 6 waves/SIMD.
// bid = 32a + 8q + b: rowtile = 8a + b, jq = q -> the 4 j-siblings of a
// rowtile share XCD (bid%8 = b) -> comb tile L2-hot after first touch.
// PRE: staging via 4 global_load_lds/wave from pre-swizzled comb.
// ---------------------------------------------------------------------------
template<bool PRE>
__global__ void __launch_bounds__(256, 6)
lstm_main(const short* __restrict__ comb,
          const float* __restrict__ inp, const float* __restrict__ hid,
          const float* __restrict__ cell, const short* __restrict__ Bp,
          const float* __restrict__ bfv, const float* __restrict__ bcv,
          const float* __restrict__ biv, const float* __restrict__ bov,
          float* __restrict__ out)
{
    __shared__ short As[32 * 256];      // 16 KB swizzled combine tile

    const int tid  = threadIdx.x;
    const int lane = tid & 63;
    const int wave = tid >> 6;          // 0..3
    const int lm   = lane & 15;
    const int lk   = lane >> 4;

    const int bid     = blockIdx.x;
    const int jq      = (bid >> 3) & 3;
    const int rowtile = (bid >> 5) * 8 + (bid & 7);
    const int rowblk  = rowtile * 32;

    const int j         = jq * 64 + wave * 16 + lm;   // this lane's gate-col
    const int jf_global = jq * 4 + wave;              // j / 16

    if (PRE) {
        // stage 16 KB tile: 16 x global_load_lds_dwordx4 (4 per wave), linear
        const char* tsrc = reinterpret_cast<const char*>(comb) + (size_t)rowtile * 16384;
#pragma unroll
        for (int i = 0; i < 4; ++i) {
            int off = (wave * 4 + i) * 1024;
            __builtin_amdgcn_global_load_lds(
                (const __attribute__((address_space(1))) void*)(tsrc + off + lane * 16),
                (__attribute__((address_space(3))) void*)(reinterpret_cast<char*>(As) + off),
                16, 0, 0);
        }
    }

    // bias per lane (j fixed per lane) — latency drains with the barrier
    const float bF = bfv[j], bC = bcv[j], bI = biv[j], bO = bov[j];

    if (PRE) __syncthreads();           // As visible (gll drained)

    f32x4 acc[4][2];                    // [gate][mf] = 32 VGPRs
    acc[0][0] = (f32x4){bF, bF, bF, bF};
    acc[1][0] = (f32x4){bC, bC, bC, bC};
    acc[2][0] = (f32x4){bI, bI, bI, bI};
    acc[3][0] = (f32x4){bO, bO, bO, bO};
#pragma unroll
    for (int g = 0; g < 4; ++g) acc[g][1] = acc[g][0];

    // ---- GEMM: K=256 in 8 steps ------------------------------------------
#pragma unroll
    for (int ks = 0; ks < 8; ++ks) {
        short8 cf[2];
#pragma unroll
        for (int mf = 0; mf < 2; ++mf) {
            if (PRE) {
                int row  = mf * 16 + lm;
                int byte = (row * 512 + (ks * 32 + lk * 8) * 2) ^ ((row & 7) << 4);
                cf[mf] = *reinterpret_cast<const short8*>(
                             reinterpret_cast<const char*>(As) + byte);
            } else {
                int row = rowblk + mf * 16 + lm;
                const float* ipr = inp + (size_t)row * Hdim + ks * 32 + lk * 8;
                const float* hpr = hid + (size_t)row * Hdim + ks * 32 + lk * 8;
                float4 a0 = *reinterpret_cast<const float4*>(ipr);
                float4 a1 = *reinterpret_cast<const float4*>(ipr + 4);
                float4 h0 = *reinterpret_cast<const float4*>(hpr);
                float4 h1 = *reinterpret_cast<const float4*>(hpr + 4);
                short8 v;
                v[0] = f2bf(a0.x + h0.x);
                v[1] = f2bf(a0.y + h0.y);
                v[2] = f2bf(a0.z + h0.z);
                v[3] = f2bf(a0.w + h0.w);
                v[4] = f2bf(a1.x + h1.x);
                v[5] = f2bf(a1.y + h1.y);
                v[6] = f2bf(a1.z + h1.z);
                v[7] = f2bf(a1.w + h1.w);
                cf[mf] = v;
            }
        }
#pragma unroll
        for (int g = 0; g < 4; ++g) {
            int chunk = (g * 8 + ks) * 16 + jf_global;
            short8 b = *reinterpret_cast<const short8*>(
                           Bp + ((size_t)chunk * 64 + lane) * 8);   // 1KB/wave contig
            acc[g][0] = __builtin_amdgcn_mfma_f32_16x16x32_bf16(cf[0], b, acc[g][0], 0, 0, 0);
            acc[g][1] = __builtin_amdgcn_mfma_f32_16x16x32_bf16(cf[1], b, acc[g][1], 0, 0, 0);
        }
    }

    // ---- cell loads (8 scalar, 64B-coalesced across lm) -------------------
    float cv[2][4];
#pragma unroll
    for (int mf = 0; mf < 2; ++mf)
#pragma unroll
        for (int r = 0; r < 4; ++r)
            cv[mf][r] = cell[(size_t)(rowblk + mf * 16 + lk * 4 + r) * Hdim + j];

    // ---- epilogue: gates + states, scalar fp32 stores ---------------------
    float* out0 = out;                               // out gate
    float* out1 = out + (size_t)Bsz * Hdim;          // hidden_state
    float* out2 = out + (size_t)2 * Bsz * Hdim;      // cell_state

#pragma unroll
    for (int mf = 0; mf < 2; ++mf) {
#pragma unroll
        for (int r = 0; r < 4; ++r) {
            int row = rowblk + mf * 16 + lk * 4 + r;   // C/D: row=(lane>>4)*4+reg
            size_t off = (size_t)row * Hdim + j;
            float F = sigm(acc[0][mf][r]);
            float C = tanh_fast(acc[1][mf][r]);
            float I = sigm(sigm(acc[2][mf][r]));       // double sigmoid, per ref
            float O = sigm(acc[3][mf][r]);
            float cs = cv[mf][r] * F + C * I;
            float hs = O * tanh_fast(cs);
            out0[off] = O;
            out1[off] = hs;
            out2[off] = cs;
        }
    }
}

extern "C" void kernel_launch(void* const* d_in, const int* in_sizes, int n_in,
                              void* d_out, int out_size, void* d_ws, size_t ws_size,
                              hipStream_t stream)
{
    const float* inp  = (const float*)d_in[0];
    const float* hid  = (const float*)d_in[1];
    const float* cell = (const float*)d_in[2];
    const float* Wf   = (const float*)d_in[3];
    const float* bf_  = (const float*)d_in[4];
    const float* Wc   = (const float*)d_in[5];
    const float* bc_  = (const float*)d_in[6];
    const float* Wi   = (const float*)d_in[7];
    const float* bi_  = (const float*)d_in[8];
    const float* Wo   = (const float*)d_in[9];
    const float* bo_  = (const float*)d_in[10];
    float* outp = (float*)d_out;

    const int NBLK = (Bsz / 32) * 4;   // 8192

    if (ws_size >= WS_NEED) {
        short* comb = (short*)d_ws;                   // 33.5 MB pre-swizzled bf16
        short* Bp   = comb + COMB_SHORTS;             // 512 KB packed weights
        prep_kernel<<<1024 + Bsz * Hdim / (256 * 8), 256, 0, stream>>>(
            inp, hid, Wf, Wc, Wi, Wo, comb, Bp);
        lstm_main<true><<<NBLK, 256, 0, stream>>>(comb, inp, hid, cell, Bp,
                                                  bf_, bc_, bi_, bo_, outp);
    } else {
        short* Bp = (short*)d_ws;
        prep_kernel<<<1024, 256, 0, stream>>>(inp, hid, Wf, Wc, Wi, Wo, nullptr, Bp);
        lstm_main<false><<<NBLK, 256, 0, stream>>>(nullptr, inp, hid, cell, Bp,
                                                   bf_, bc_, bi_, bo_, outp);
    }
}

// Round 10
// 143.164 us; speedup vs baseline: 1.0957x; 1.0957x over previous
//
#include <hip/hip_runtime.h>
#include <hip/hip_bf16.h>

// LSTM cell fused kernel for MI355X (gfx950).
// B=65536, H=256. Packed GEMM [B,256]x[256,1024] bf16 MFMA + fused gates.
// R10: single kernel. 8192 blocks x 256 thr, tile 32r x 64j (jq quarters,
//      XCD-paired). In-kernel reg staging; DEPTH-2 weight register pipeline
//      (bA/bB) to kill the per-K-step L2 latency exposure; cell/bias loads
//      pre-barrier; v_rcp_f32-based gates (no slow fp32 div sequence).

typedef __attribute__((ext_vector_type(8))) short short8;   // 8 bf16
typedef __attribute__((ext_vector_type(4))) float f32x4;

static constexpr int Bsz  = 65536;
static constexpr int Hdim = 256;

// float -> bf16 bits, round-to-nearest-even
__device__ __forceinline__ short f2bf(float f) {
    unsigned u = __float_as_uint(f);
    return (short)((u + 0x7FFFu + ((u >> 16) & 1u)) >> 16);
}
__device__ __forceinline__ float fast_rcp(float x) {
    float r;
    asm("v_rcp_f32 %0, %1" : "=v"(r) : "v"(x));
    return r;
}
__device__ __forceinline__ float sigm(float x) {
    return fast_rcp(1.0f + __expf(-x));
}
__device__ __forceinline__ float tanh_fast(float x) {
    return 2.0f * fast_rcp(1.0f + __expf(-2.0f * x)) - 1.0f;
}

// ---------------------------------------------------------------------------
// Pack Wf,Wc,Wi,Wo ([256,256] fp32) into bf16 B-fragment-major layout for
// mfma_f32_16x16x32_bf16 (verified R2..R9):
//   flat o = (((g*8 + ks)*16 + jf)*64 + lane)*8 + e
//   k = ks*32 + (lane>>4)*8 + e ;  j = jf*16 + (lane&15) ;  B[k][j] = W_g[j][k]
// ---------------------------------------------------------------------------
__global__ void __launch_bounds__(256)
prep_w_kernel(const float* __restrict__ Wf, const float* __restrict__ Wc,
              const float* __restrict__ Wi, const float* __restrict__ Wo,
              short* __restrict__ Bp)
{
    int o    = blockIdx.x * 256 + threadIdx.x;   // 0 .. 262143
    int e    = o & 7;
    int lane = (o >> 3) & 63;
    int jf   = (o >> 9) & 15;
    int ks   = (o >> 13) & 7;
    int g    = (o >> 16) & 3;
    int k = ks * 32 + (lane >> 4) * 8 + e;
    int j = jf * 16 + (lane & 15);
    const float* W = (g == 0) ? Wf : (g == 1) ? Wc : (g == 2) ? Wi : Wo;
    Bp[o] = f2bf(W[j * 256 + k]);
}

// ---------------------------------------------------------------------------
// Main. 8192 blocks x 256 threads (4 waves). Block = 32 rows x 64 gate-cols
// (one j-quarter) x 4 gates; wave owns 16 j. acc[4][2] = 32 VGPRs.
// bid = 32a + 8q + b: rowtile = 8a + b, jq = q -> the 4 j-siblings of a
// rowtile share an XCD -> combine re-reads are L2-hit; output lines complete.
// ---------------------------------------------------------------------------
__global__ void __launch_bounds__(256, 4)
lstm_main(const float* __restrict__ inp, const float* __restrict__ hid,
          const float* __restrict__ cell, const short* __restrict__ Bp,
          const float* __restrict__ bfv, const float* __restrict__ bcv,
          const float* __restrict__ biv, const float* __restrict__ bov,
          float* __restrict__ out)
{
    __shared__ short As[32 * 256];      // 16 KB swizzled combine tile

    const int tid  = threadIdx.x;
    const int lane = tid & 63;
    const int wave = tid >> 6;          // 0..3
    const int lm   = lane & 15;
    const int lk   = lane >> 4;

    const int bid     = blockIdx.x;
    const int jq      = (bid >> 3) & 3;
    const int rowtile = (bid >> 5) * 8 + (bid & 7);
    const int rowblk  = rowtile * 32;

    const int j         = jq * 64 + wave * 16 + lm;   // this lane's gate-col
    const int jf_global = jq * 4 + wave;              // j / 16

    // ---- stage combine = input + hidden (bf16) into LDS, XOR-swizzled -----
    // 1024 chunks of 8 elems; 256 threads -> 4 chunks each; 16 loads in flight.
    float4 Li[4][2], Lh[4][2];
#pragma unroll
    for (int c = 0; c < 4; ++c) {
        int cc  = tid + c * 256;         // chunk 0..1023
        int row = cc >> 5;               // 0..31
        int k0  = (cc & 31) * 8;         // 0..248
        const float4* ip = reinterpret_cast<const float4*>(inp + (size_t)(rowblk + row) * Hdim + k0);
        const float4* hp = reinterpret_cast<const float4*>(hid + (size_t)(rowblk + row) * Hdim + k0);
        Li[c][0] = ip[0]; Li[c][1] = ip[1];
        Lh[c][0] = hp[0]; Lh[c][1] = hp[1];
    }
    // cell + bias issued behind staging loads: latency drains with barrier
    float cv[2][4];
#pragma unroll
    for (int mf = 0; mf < 2; ++mf)
#pragma unroll
        for (int r = 0; r < 4; ++r)
            cv[mf][r] = cell[(size_t)(rowblk + mf * 16 + lk * 4 + r) * Hdim + j];
    const float bF = bfv[j], bC = bcv[j], bI = biv[j], bO = bov[j];

#pragma unroll
    for (int c = 0; c < 4; ++c) {
        int cc  = tid + c * 256;
        int row = cc >> 5;
        int k0  = (cc & 31) * 8;
        short8 v;
        v[0] = f2bf(Li[c][0].x + Lh[c][0].x);
        v[1] = f2bf(Li[c][0].y + Lh[c][0].y);
        v[2] = f2bf(Li[c][0].z + Lh[c][0].z);
        v[3] = f2bf(Li[c][0].w + Lh[c][0].w);
        v[4] = f2bf(Li[c][1].x + Lh[c][1].x);
        v[5] = f2bf(Li[c][1].y + Lh[c][1].y);
        v[6] = f2bf(Li[c][1].z + Lh[c][1].z);
        v[7] = f2bf(Li[c][1].w + Lh[c][1].w);
        int byte = (row * 512 + k0 * 2) ^ ((row & 7) << 4);
        *reinterpret_cast<short8*>(reinterpret_cast<char*>(As) + byte) = v;
    }

    __syncthreads();                     // As visible; cv/bias drained too

    // ---- acc init = bias --------------------------------------------------
    f32x4 acc[4][2];                     // [gate][mf] = 32 VGPRs
    acc[0][0] = (f32x4){bF, bF, bF, bF};
    acc[1][0] = (f32x4){bC, bC, bC, bC};
    acc[2][0] = (f32x4){bI, bI, bI, bI};
    acc[3][0] = (f32x4){bO, bO, bO, bO};
#pragma unroll
    for (int g = 0; g < 4; ++g) acc[g][1] = acc[g][0];

    // ---- GEMM: K=256 in 8 steps, DEPTH-2 weight register pipeline ---------
    const char* A = reinterpret_cast<const char*>(As);
    auto wload = [&](int g, int ks) -> short8 {
        int chunk = (g * 8 + ks) * 16 + jf_global;
        return *reinterpret_cast<const short8*>(Bp + ((size_t)chunk * 64 + lane) * 8);
    };
    auto aload = [&](int mf, int ks) -> short8 {
        int row  = mf * 16 + lm;
        int byte = (row * 512 + (ks * 32 + lk * 8) * 2) ^ ((row & 7) << 4);
        return *reinterpret_cast<const short8*>(A + byte);
    };

    short8 bA0 = wload(0, 0), bA1 = wload(1, 0), bA2 = wload(2, 0), bA3 = wload(3, 0);

#pragma unroll
    for (int ks2 = 0; ks2 < 8; ks2 += 2) {
        // step ks2: read A-frags, issue next step's weights, then MFMA
        short8 cf0[2] = { aload(0, ks2), aload(1, ks2) };
        short8 bB0 = wload(0, ks2 + 1), bB1 = wload(1, ks2 + 1),
               bB2 = wload(2, ks2 + 1), bB3 = wload(3, ks2 + 1);
        acc[0][0] = __builtin_amdgcn_mfma_f32_16x16x32_bf16(cf0[0], bA0, acc[0][0], 0, 0, 0);
        acc[0][1] = __builtin_amdgcn_mfma_f32_16x16x32_bf16(cf0[1], bA0, acc[0][1], 0, 0, 0);
        acc[1][0] = __builtin_amdgcn_mfma_f32_16x16x32_bf16(cf0[0], bA1, acc[1][0], 0, 0, 0);
        acc[1][1] = __builtin_amdgcn_mfma_f32_16x16x32_bf16(cf0[1], bA1, acc[1][1], 0, 0, 0);
        acc[2][0] = __builtin_amdgcn_mfma_f32_16x16x32_bf16(cf0[0], bA2, acc[2][0], 0, 0, 0);
        acc[2][1] = __builtin_amdgcn_mfma_f32_16x16x32_bf16(cf0[1], bA2, acc[2][1], 0, 0, 0);
        acc[3][0] = __builtin_amdgcn_mfma_f32_16x16x32_bf16(cf0[0], bA3, acc[3][0], 0, 0, 0);
        acc[3][1] = __builtin_amdgcn_mfma_f32_16x16x32_bf16(cf0[1], bA3, acc[3][1], 0, 0, 0);

        // step ks2+1: read A-frags, issue step ks2+2's weights, MFMA with bB
        short8 cf1[2] = { aload(0, ks2 + 1), aload(1, ks2 + 1) };
        if (ks2 + 2 < 8) {
            bA0 = wload(0, ks2 + 2); bA1 = wload(1, ks2 + 2);
            bA2 = wload(2, ks2 + 2); bA3 = wload(3, ks2 + 2);
        }
        acc[0][0] = __builtin_amdgcn_mfma_f32_16x16x32_bf16(cf1[0], bB0, acc[0][0], 0, 0, 0);
        acc[0][1] = __builtin_amdgcn_mfma_f32_16x16x32_bf16(cf1[1], bB0, acc[0][1], 0, 0, 0);
        acc[1][0] = __builtin_amdgcn_mfma_f32_16x16x32_bf16(cf1[0], bB1, acc[1][0], 0, 0, 0);
        acc[1][1] = __builtin_amdgcn_mfma_f32_16x16x32_bf16(cf1[1], bB1, acc[1][1], 0, 0, 0);
        acc[2][0] = __builtin_amdgcn_mfma_f32_16x16x32_bf16(cf1[0], bB2, acc[2][0], 0, 0, 0);
        acc[2][1] = __builtin_amdgcn_mfma_f32_16x16x32_bf16(cf1[1], bB2, acc[2][1], 0, 0, 0);
        acc[3][0] = __builtin_amdgcn_mfma_f32_16x16x32_bf16(cf1[0], bB3, acc[3][0], 0, 0, 0);
        acc[3][1] = __builtin_amdgcn_mfma_f32_16x16x32_bf16(cf1[1], bB3, acc[3][1], 0, 0, 0);
    }

    // ---- epilogue: gates + states, scalar fp32 stores (full lines/block) --
    float* out0 = out;                               // out gate
    float* out1 = out + (size_t)Bsz * Hdim;          // hidden_state
    float* out2 = out + (size_t)2 * Bsz * Hdim;      // cell_state

#pragma unroll
    for (int mf = 0; mf < 2; ++mf) {
#pragma unroll
        for (int r = 0; r < 4; ++r) {
            int row = rowblk + mf * 16 + lk * 4 + r;   // C/D: row=(lane>>4)*4+reg
            size_t off = (size_t)row * Hdim + j;
            float F = sigm(acc[0][mf][r]);
            float C = tanh_fast(acc[1][mf][r]);
            float I = sigm(sigm(acc[2][mf][r]));       // double sigmoid, per ref
            float O = sigm(acc[3][mf][r]);
            float cs = cv[mf][r] * F + C * I;
            float hs = O * tanh_fast(cs);
            out0[off] = O;
            out1[off] = hs;
            out2[off] = cs;
        }
    }
}

extern "C" void kernel_launch(void* const* d_in, const int* in_sizes, int n_in,
                              void* d_out, int out_size, void* d_ws, size_t ws_size,
                              hipStream_t stream)
{
    const float* inp  = (const float*)d_in[0];
    const float* hid  = (const float*)d_in[1];
    const float* cell = (const float*)d_in[2];
    const float* Wf   = (const float*)d_in[3];
    const float* bf_  = (const float*)d_in[4];
    const float* Wc   = (const float*)d_in[5];
    const float* bc_  = (const float*)d_in[6];
    const float* Wi   = (const float*)d_in[7];
    const float* bi_  = (const float*)d_in[8];
    const float* Wo   = (const float*)d_in[9];
    const float* bo_  = (const float*)d_in[10];

    short* Bp = (short*)d_ws;    // 512 KB packed bf16 weights

    prep_w_kernel<<<1024, 256, 0, stream>>>(Wf, Wc, Wi, Wo, Bp);
    lstm_main<<<(Bsz / 32) * 4, 256, 0, stream>>>(inp, hid, cell, Bp,
                                                  bf_, bc_, bi_, bo_, (float*)d_out);
}